// Round 2
// baseline (63653.174 us; speedup 1.0000x reference)
//
#include <hip/hip_runtime.h>
#include <stdint.h>

// SimpleGRU  B=64 S=2048 I=256 H=512 O=10
//
// Phase A: xp[s][b][1536] (bf16) = x@[Wz|Wr|Wh]^T + (b*+c*)  -- fp32 register-tiled GEMM
// Phase B: persistent PLAIN-launch kernel (64 blocks <= 256 CUs, always co-resident),
//          64 blocks = 4 groups(16 batches) x 16 row-slices(32 rows).
//          U fragments weight-stationary in VGPRs (bf16), MFMA 16x16x32, fp32 master state hgf,
//          2 device-scope atomic group barriers per step (r-exchange, h-exchange).
//          NOTE: round-1 failure isolated to hipLaunchCooperativeKernel silently failing
//          (unchecked error; cooperative launches don't graph-capture). Plain launch here.

#define S_LEN  2048
#define BATCH  64
#define IDIM   256
#define HDIM   512
#define ODIM   10
#define GATES3 1536

typedef __attribute__((ext_vector_type(8))) short bf16x8;
typedef __attribute__((ext_vector_type(4))) float f32x4;

__device__ __forceinline__ unsigned short f2bf(float x) {
    unsigned int u = __float_as_uint(x);
    u += 0x7fffu + ((u >> 16) & 1u);      // RNE
    return (unsigned short)(u >> 16);
}
__device__ __forceinline__ float bf2f(unsigned short h) {
    return __uint_as_float(((unsigned int)h) << 16);
}

// ---------------------------------------------------------------------------
// Phase A: C-tile 64(bs) x 256(h) per block, thread tile 8x8 (scattered), K-panels of 32.
// ---------------------------------------------------------------------------
__global__ __launch_bounds__(256)
void proj_kernel(const float* __restrict__ x,
                 const float* __restrict__ Wz, const float* __restrict__ Wr, const float* __restrict__ Wh,
                 const float* __restrict__ bz, const float* __restrict__ cz,
                 const float* __restrict__ br, const float* __restrict__ cr,
                 const float* __restrict__ bh, const float* __restrict__ ch,
                 unsigned short* __restrict__ xp)
{
    __shared__ float xs[64][33];     // +1 pad: conflict-free
    __shared__ float wsm[256][33];
    const int tid = threadIdx.x;
    const int bs0 = blockIdx.x * 64;
    const int hc0 = blockIdx.y * 256;
    const int ty = tid >> 5;         // 0..7  -> rows {ty+8i}
    const int cx = tid & 31;         // 0..31 -> cols {cx+32j} (lane-stride-1 -> LDS conflict-free)

    const int h = hc0 + tid;
    const int gate = h >> 9;
    const int hl = h & 511;
    const float* Wgrow = (gate == 0 ? Wz : (gate == 1 ? Wr : Wh)) + (size_t)hl * IDIM;

    float acc[8][8];
#pragma unroll
    for (int i = 0; i < 8; ++i)
#pragma unroll
        for (int jj = 0; jj < 8; ++jj) acc[i][jj] = 0.f;

    for (int kp = 0; kp < IDIM; kp += 32) {
        {   // stage x panel: 64 rows x 32
            const int r = tid >> 2;
            const int kq = (tid & 3) * 8;
            const float* src = x + (size_t)(bs0 + r) * IDIM + kp + kq;
#pragma unroll
            for (int e = 0; e < 8; ++e) xs[r][kq + e] = src[e];
        }
        {   // stage W panel: 256 rows x 32, one row per thread
            const float* src = Wgrow + kp;
#pragma unroll
            for (int e = 0; e < 32; ++e) wsm[tid][e] = src[e];
        }
        __syncthreads();
#pragma unroll
        for (int k = 0; k < 32; ++k) {
            float xa[8], wb[8];
#pragma unroll
            for (int i = 0; i < 8; ++i) xa[i] = xs[ty + 8 * i][k];          // broadcast
#pragma unroll
            for (int jj = 0; jj < 8; ++jj) wb[jj] = wsm[cx + 32 * jj][k];   // bank = (cx+k)%32
#pragma unroll
            for (int i = 0; i < 8; ++i)
#pragma unroll
                for (int jj = 0; jj < 8; ++jj) acc[i][jj] += xa[i] * wb[jj];
        }
        __syncthreads();
    }
    // epilogue: + (input bias + recurrent bias folded), store bf16
#pragma unroll
    for (int jj = 0; jj < 8; ++jj) {
        const int hh = hc0 + cx + 32 * jj;
        const int gg = hh >> 9;
        const int hhl = hh & 511;
        const float bias = (gg == 0 ? bz[hhl] + cz[hhl]
                          : gg == 1 ? br[hhl] + cr[hhl]
                                    : bh[hhl] + ch[hhl]);
#pragma unroll
        for (int i = 0; i < 8; ++i) {
            const int rrow = bs0 + ty + 8 * i;
            const int b = rrow >> 11;     // /S
            const int s = rrow & 2047;    // %S
            xp[(size_t)s * (BATCH * GATES3) + (size_t)b * GATES3 + hh] = f2bf(acc[i][jj] + bias);
        }
    }
}

// ---------------------------------------------------------------------------
// Phase B: persistent recurrence.
// 64 blocks: g = blockIdx&3 (batches 16g..), j = blockIdx>>2 (U rows 32j..32j+31).
// Wave roles (4 waves/block): w0,w1 = z-gate ntile 0/1 then h~ ntile 0/1; w2,w3 = r-gate ntile 0/1.
// MFMA 16x16x32: A[m=lane&15][k=quad*8+jv]; B[k=quad*8+jv][n=lane&15]; D col=lane&15,row=quad*4+reg.
// ---------------------------------------------------------------------------
__global__ __launch_bounds__(256)
void gru_recur(const float* __restrict__ Uz, const float* __restrict__ Ur,
               const float* __restrict__ Uh,
               const unsigned short* __restrict__ xp,
               unsigned short* __restrict__ hg,    // bf16 mirror of state [64][512]
               unsigned short* __restrict__ rhg,   // bf16 r*h            [64][512]
               float* __restrict__ hgf,            // fp32 master state   [64][512]
               unsigned int* __restrict__ ctr,     // group barrier counters (64B apart)
               const float* __restrict__ Wf, const float* __restrict__ bfv,
               float* __restrict__ out)
{
    const int tid  = threadIdx.x;
    const int wave = tid >> 6;
    const int lane = tid & 63;
    const int quad = lane >> 4;
    const int l16  = lane & 15;
    const int g  = blockIdx.x & 3;
    const int j  = blockIdx.x >> 2;
    const int b0 = g * 16;
    const int i0 = j * 32;
    const int nt = wave & 1;
    const bool isZ = (wave < 2);

    // ---- one-time: weight B-fragments into registers (weight-stationary) ----
    const int wrow = i0 + nt * 16 + l16;   // n = lane&15
    const int kofs = quad * 8;
    bf16x8 wp1[16], wp2[16];
    const float* U1 = isZ ? Uz : Ur;
#pragma unroll
    for (int kb = 0; kb < 16; ++kb) {
        const float* s1 = U1 + (size_t)wrow * HDIM + kb * 32 + kofs;
        const float* s2 = Uh + (size_t)wrow * HDIM + kb * 32 + kofs;
        bf16x8 w1, w2;
#pragma unroll
        for (int e = 0; e < 8; ++e) {
            w1[e] = (short)f2bf(s1[e]);
            w2[e] = (short)f2bf(s2[e]);
        }
        wp1[kb] = w1; wp2[kb] = w2;
    }

    unsigned int* myctr = ctr + g * 16;
    const int iloc = nt * 16 + l16;
    const int icol = i0 + iloc;
    float zfrag[4] = {0.f, 0.f, 0.f, 0.f};

    for (int t = 0; t < S_LEN; ++t) {
        const size_t xbase = (size_t)t * (BATCH * GATES3);

        // -------- phase 1: z (w0,w1) / r (w2,w3) --------
        f32x4 c1 = {0.f, 0.f, 0.f, 0.f};
#pragma unroll
        for (int kb = 0; kb < 16; ++kb) {
            const bf16x8 a = *(const bf16x8*)(const void*)(hg + (size_t)(b0 + l16) * HDIM + kb * 32 + kofs);
            c1 = __builtin_amdgcn_mfma_f32_16x16x32_bf16(a, wp1[kb], c1, 0, 0, 0);
        }
        const int gofs = isZ ? 0 : HDIM;
#pragma unroll
        for (int r = 0; r < 4; ++r) {
            const int b = b0 + quad * 4 + r;
            const float pre = c1[r] + bf2f(xp[xbase + (size_t)b * GATES3 + gofs + icol]);
            const float v = 1.f / (1.f + __expf(-pre));
            if (isZ) {
                zfrag[r] = v;
            } else {
                const float ho = hgf[b * HDIM + icol];
                rhg[b * HDIM + icol] = f2bf(v * ho);
            }
        }
        __threadfence();
        __syncthreads();
        if (tid == 0) {
            __hip_atomic_fetch_add(myctr, 1u, __ATOMIC_RELEASE, __HIP_MEMORY_SCOPE_AGENT);
            const unsigned int target = 16u * (2u * (unsigned)t + 1u);
            while (__hip_atomic_load(myctr, __ATOMIC_ACQUIRE, __HIP_MEMORY_SCOPE_AGENT) < target)
                __builtin_amdgcn_s_sleep(2);
        }
        __syncthreads();
        __threadfence();   // acquire side: drain + invalidate stale L1 copies

        // -------- phase 2: h~ + state update (w0,w1 only) --------
        if (isZ) {
            f32x4 c2 = {0.f, 0.f, 0.f, 0.f};
#pragma unroll
            for (int kb = 0; kb < 16; ++kb) {
                const bf16x8 a = *(const bf16x8*)(const void*)(rhg + (size_t)(b0 + l16) * HDIM + kb * 32 + kofs);
                c2 = __builtin_amdgcn_mfma_f32_16x16x32_bf16(a, wp2[kb], c2, 0, 0, 0);
            }
#pragma unroll
            for (int r = 0; r < 4; ++r) {
                const int b = b0 + quad * 4 + r;
                const float pre = c2[r] + bf2f(xp[xbase + (size_t)b * GATES3 + 2 * HDIM + icol]);
                const float ht = tanhf(pre);
                const float ho = hgf[b * HDIM + icol];
                const float hn = ho + zfrag[r] * (ht - ho);
                hgf[b * HDIM + icol] = hn;        // fp32 master state (no compounding quantization)
                hg[b * HDIM + icol]  = f2bf(hn);  // bf16 mirror for MFMA A-frags
            }
        }
        __threadfence();
        __syncthreads();
        if (tid == 0) {
            __hip_atomic_fetch_add(myctr, 1u, __ATOMIC_RELEASE, __HIP_MEMORY_SCOPE_AGENT);
            const unsigned int target = 16u * (2u * (unsigned)t + 2u);
            while (__hip_atomic_load(myctr, __ATOMIC_ACQUIRE, __HIP_MEMORY_SCOPE_AGENT) < target)
                __builtin_amdgcn_s_sleep(2);
        }
        __syncthreads();
        __threadfence();
    }

    // -------- final projection: out = h_T @ Wf^T + bf (fp32), one block per group --------
    if (j == 0 && tid < 16 * ODIM) {
        const int b = b0 + tid / ODIM;
        const int o = tid % ODIM;
        float acc = bfv[o];
        for (int k = 0; k < HDIM; ++k)
            acc += hgf[b * HDIM + k] * Wf[o * HDIM + k];
        out[b * ODIM + o] = acc;
    }
}

// ---------------------------------------------------------------------------
extern "C" void kernel_launch(void* const* d_in, const int* in_sizes, int n_in,
                              void* d_out, int out_size, void* d_ws, size_t ws_size,
                              hipStream_t stream)
{
    const float* x  = (const float*)d_in[0];
    const float* Wz = (const float*)d_in[1];
    const float* bz = (const float*)d_in[2];
    const float* Uz = (const float*)d_in[3];
    const float* cz = (const float*)d_in[4];
    const float* Wr = (const float*)d_in[5];
    const float* br = (const float*)d_in[6];
    const float* Ur = (const float*)d_in[7];
    const float* cr = (const float*)d_in[8];
    const float* Wh = (const float*)d_in[9];
    const float* bh = (const float*)d_in[10];
    const float* Uh = (const float*)d_in[11];
    const float* ch = (const float*)d_in[12];
    const float* Wf = (const float*)d_in[13];
    const float* bf = (const float*)d_in[14];
    float* out = (float*)d_out;

    char* ws = (char*)d_ws;
    const size_t XPB = (size_t)S_LEN * BATCH * GATES3 * sizeof(unsigned short); // 402,653,184 B
    unsigned short* xp  = (unsigned short*)ws;
    unsigned short* hg  = (unsigned short*)(ws + XPB);
    unsigned short* rhg = (unsigned short*)(ws + XPB + 65536);
    float*          hgf = (float*)(ws + XPB + 131072);
    unsigned int*   ctr = (unsigned int*)(ws + XPB + 262144);
    // total ws need: XPB + 262144 + 256 ~= 403 MB (round-1 memset at this offset succeeded -> fits)

    // zero h state (h0 = 0) + barrier counters (ws is poisoned 0xAA before every launch)
    hipMemsetAsync(ws + XPB, 0, 262144 + 256, stream);

    proj_kernel<<<dim3((BATCH * S_LEN) / 64, GATES3 / 256), 256, 0, stream>>>(
        x, Wz, Wr, Wh, bz, cz, br, cr, bh, ch, xp);

    // Plain launch: 64 blocks on 256 CUs are always co-resident; sync is via
    // device-scope atomics only (no cooperative-groups API used).
    gru_recur<<<dim3(64), dim3(256), 0, stream>>>(
        Uz, Ur, Uh, xp, hg, rhg, hgf, ctr, Wf, bf, out);
}

// Round 3
// 23992.860 us; speedup vs baseline: 2.6530x; 2.6530x over previous
//
#include <hip/hip_runtime.h>
#include <stdint.h>

// SimpleGRU  B=64 S=2048 I=256 H=512 O=10
//
// Phase A: xp2[s][1536][64] (bf16) = x@[Wz|Wr|Wh]^T + (b*+c*)  -- fp32 register-tiled GEMM
// Phase B: persistent plain-launch kernel, 64 blocks = 4 groups(16 batches) x 16 col-slices(32).
//   R2 lesson: __threadfence() on gfx950 = full L2 writeback+invalidate (buffer_wbl2/inv),
//   ~29 us/step, WRITE_SIZE 532 MB. Fix: NO fences. All cross-block data moves via relaxed
//   agent-scope atomics (cache-bypassing sc0/sc1 accesses to the device coherence point).
//   Barrier = __syncthreads (drains vmcnt) -> per-block flag store -> wave0 spins on 16 flags.
//   h master fp32 lives in w0/w1 registers + block-local LDS for the r-waves.

#define S_LEN  2048
#define BATCH  64
#define IDIM   256
#define HDIM   512
#define ODIM   10
#define GATES3 1536

typedef __attribute__((ext_vector_type(8))) short bf16x8;
typedef __attribute__((ext_vector_type(4))) float f32x4;

__device__ __forceinline__ unsigned short f2bf(float x) {
    unsigned int u = __float_as_uint(x);
    u += 0x7fffu + ((u >> 16) & 1u);      // RNE
    return (unsigned short)(u >> 16);
}
__device__ __forceinline__ float bf2f(unsigned short h) {
    return __uint_as_float(((unsigned int)h) << 16);
}

// Cache-bypassing device-coherent accesses (relaxed agent atomics -> sc0 sc1 global ops).
__device__ __forceinline__ unsigned long long g_load64(const void* p) {
    return __hip_atomic_load((const unsigned long long*)p, __ATOMIC_RELAXED, __HIP_MEMORY_SCOPE_AGENT);
}
__device__ __forceinline__ unsigned int g_load32(const void* p) {
    return __hip_atomic_load((const unsigned int*)p, __ATOMIC_RELAXED, __HIP_MEMORY_SCOPE_AGENT);
}
__device__ __forceinline__ void g_store32(void* p, unsigned int v) {
    __hip_atomic_store((unsigned int*)p, v, __ATOMIC_RELAXED, __HIP_MEMORY_SCOPE_AGENT);
}

// ---------------------------------------------------------------------------
// Phase A: C-tile 64(bs) x 256(h) per block, thread tile 8x8 (scattered), K-panels of 32.
// ---------------------------------------------------------------------------
__global__ __launch_bounds__(256)
void proj_kernel(const float* __restrict__ x,
                 const float* __restrict__ Wz, const float* __restrict__ Wr, const float* __restrict__ Wh,
                 const float* __restrict__ bz, const float* __restrict__ cz,
                 const float* __restrict__ br, const float* __restrict__ cr,
                 const float* __restrict__ bh, const float* __restrict__ ch,
                 unsigned short* __restrict__ xp)
{
    __shared__ float xs[64][33];
    __shared__ float wsm[256][33];
    const int tid = threadIdx.x;
    const int bs0 = blockIdx.x * 64;
    const int hc0 = blockIdx.y * 256;
    const int ty = tid >> 5;
    const int cx = tid & 31;

    const int h = hc0 + tid;
    const int gate = h >> 9;
    const int hl = h & 511;
    const float* Wgrow = (gate == 0 ? Wz : (gate == 1 ? Wr : Wh)) + (size_t)hl * IDIM;

    float acc[8][8];
#pragma unroll
    for (int i = 0; i < 8; ++i)
#pragma unroll
        for (int jj = 0; jj < 8; ++jj) acc[i][jj] = 0.f;

    for (int kp = 0; kp < IDIM; kp += 32) {
        {
            const int r = tid >> 2;
            const int kq = (tid & 3) * 8;
            const float* src = x + (size_t)(bs0 + r) * IDIM + kp + kq;
#pragma unroll
            for (int e = 0; e < 8; ++e) xs[r][kq + e] = src[e];
        }
        {
            const float* src = Wgrow + kp;
#pragma unroll
            for (int e = 0; e < 32; ++e) wsm[tid][e] = src[e];
        }
        __syncthreads();
#pragma unroll
        for (int k = 0; k < 32; ++k) {
            float xa[8], wb[8];
#pragma unroll
            for (int i = 0; i < 8; ++i) xa[i] = xs[ty + 8 * i][k];
#pragma unroll
            for (int jj = 0; jj < 8; ++jj) wb[jj] = wsm[cx + 32 * jj][k];
#pragma unroll
            for (int i = 0; i < 8; ++i)
#pragma unroll
                for (int jj = 0; jj < 8; ++jj) acc[i][jj] += xa[i] * wb[jj];
        }
        __syncthreads();
    }
    // epilogue: bias fold, store bf16 TRANSPOSED: xp2[s][h][b]
#pragma unroll
    for (int jj = 0; jj < 8; ++jj) {
        const int hh = hc0 + cx + 32 * jj;
        const int gg = hh >> 9;
        const int hhl = hh & 511;
        const float bias = (gg == 0 ? bz[hhl] + cz[hhl]
                          : gg == 1 ? br[hhl] + cr[hhl]
                                    : bh[hhl] + ch[hhl]);
#pragma unroll
        for (int i = 0; i < 8; ++i) {
            const int rrow = bs0 + ty + 8 * i;
            const int b = rrow >> 11;     // /S
            const int s = rrow & 2047;    // %S
            xp[((size_t)s * GATES3 + hh) * BATCH + b] = f2bf(acc[i][jj] + bias);
        }
    }
}

// ---------------------------------------------------------------------------
// Phase B barrier: flags[g][j] (64 B apart). No fences: data was written with
// bypassing stores; __syncthreads drains each wave's vmcnt before s_barrier.
// ---------------------------------------------------------------------------
__device__ __forceinline__ void group_barrier(unsigned int* flags, int g, int j,
                                              unsigned int epoch, int tid)
{
    __syncthreads();                               // drain all waves' global stores
    if (tid < 64) {                                // wave 0 spins
        if (tid == 0)
            __hip_atomic_store(&flags[(g * 16 + j) * 16], epoch,
                               __ATOMIC_RELAXED, __HIP_MEMORY_SCOPE_AGENT);
        const unsigned int* f = &flags[(g * 16 + (tid & 15)) * 16];
        while (__hip_atomic_load(f, __ATOMIC_RELAXED, __HIP_MEMORY_SCOPE_AGENT) < epoch) { }
    }
    __syncthreads();
}

// ---------------------------------------------------------------------------
// Phase B: 64 blocks: g = blockIdx&3 (batches 16g..), j = blockIdx>>2 (cols 32j..).
// Waves: w0,w1 = z-gate (nt 0/1) then h~ + update; w2,w3 = r-gate (nt 0/1).
// MFMA 16x16x32: A[m=lane&15][k=quad*8+e]; D col=lane&15,row=quad*4+r.
// ---------------------------------------------------------------------------
__global__ __launch_bounds__(256)
void gru_recur(const float* __restrict__ Uz, const float* __restrict__ Ur,
               const float* __restrict__ Uh,
               const unsigned short* __restrict__ xp2,  // [s][1536][64] bf16
               unsigned short* __restrict__ hg,         // bf16 h        [64][512]
               unsigned short* __restrict__ rhg,        // bf16 r*h      [64][512]
               float* __restrict__ hgf,                 // fp32 final h  [64][512]
               unsigned int* __restrict__ flags,
               const float* __restrict__ Wf, const float* __restrict__ bfv,
               float* __restrict__ out)
{
    __shared__ float hlds[16][33];   // fp32 h for r-waves, +1 pad
    const int tid  = threadIdx.x;
    const int wave = tid >> 6;
    const int lane = tid & 63;
    const int quad = lane >> 4;
    const int l16  = lane & 15;
    const int g  = blockIdx.x & 3;
    const int j  = blockIdx.x >> 2;
    const int b0 = g * 16;
    const int i0 = j * 32;
    const int nt = wave & 1;
    const bool isZ = (wave < 2);

    for (int i = tid; i < 16 * 33; i += 256) (&hlds[0][0])[i] = 0.f;

    // ---- weight B-fragments, stationary in VGPRs ----
    const int wrow = i0 + nt * 16 + l16;   // n = lane&15
    const int kofs = quad * 8;
    bf16x8 wp1[16], wp2[16];
    const float* U1 = isZ ? Uz : Ur;
#pragma unroll
    for (int kb = 0; kb < 16; ++kb) {
        const float* s1 = U1 + (size_t)wrow * HDIM + kb * 32 + kofs;
        const float* s2 = Uh + (size_t)wrow * HDIM + kb * 32 + kofs;
        bf16x8 w1, w2;
#pragma unroll
        for (int e = 0; e < 8; ++e) {
            w1[e] = (short)f2bf(s1[e]);
            w2[e] = (short)f2bf(s2[e]);
        }
        wp1[kb] = w1; wp2[kb] = w2;
    }
    __syncthreads();   // hlds zero-init visible

    const int iloc = nt * 16 + l16;
    const int icol = i0 + iloc;
    float zfrag[4];
    float hm[4] = {0.f, 0.f, 0.f, 0.f};    // fp32 master h (w0/w1 only)

    for (int t = 0; t < S_LEN; ++t) {
        // ======== phase 1: z (w0,w1) / r (w2,w3) ========
        union { unsigned long long q; unsigned short s[4]; } xq;
        xq.q = *(const unsigned long long*)(xp2 +
                 ((size_t)t * GATES3 + (isZ ? 0 : HDIM) + icol) * BATCH + b0 + quad * 4);

        f32x4 c1 = {0.f, 0.f, 0.f, 0.f};
#pragma unroll
        for (int kb = 0; kb < 16; ++kb) {
            union { unsigned long long q[2]; bf16x8 v; } a;
            const unsigned short* ap = hg + (size_t)(b0 + l16) * HDIM + kb * 32 + kofs;
            a.q[0] = g_load64(ap);
            a.q[1] = g_load64(ap + 4);
            c1 = __builtin_amdgcn_mfma_f32_16x16x32_bf16(a.v, wp1[kb], c1, 0, 0, 0);
        }
        if (isZ) {
#pragma unroll
            for (int r = 0; r < 4; ++r) {
                const float pre = c1[r] + bf2f(xq.s[r]);
                zfrag[r] = 1.f / (1.f + __expf(-pre));
            }
        } else {
            float rh[4];
#pragma unroll
            for (int r = 0; r < 4; ++r) {
                const float pre = c1[r] + bf2f(xq.s[r]);
                const float v = 1.f / (1.f + __expf(-pre));
                rh[r] = v * hlds[quad * 4 + r][iloc];
            }
#pragma unroll
            for (int r = 0; r < 4; ++r) {
                unsigned int my = f2bf(rh[r]);
                unsigned int other = (unsigned int)__shfl_xor((int)my, 1, 64);
                if ((l16 & 1) == 0)
                    g_store32(rhg + (size_t)(b0 + quad * 4 + r) * HDIM + icol, my | (other << 16));
            }
        }
        group_barrier(flags, g, j, 2u * t + 1u, tid);

        // ======== phase 2: h~ + state update (w0,w1) ========
        if (isZ) {
            union { unsigned long long q; unsigned short s[4]; } xh;
            xh.q = *(const unsigned long long*)(xp2 +
                     ((size_t)t * GATES3 + 2 * HDIM + icol) * BATCH + b0 + quad * 4);
            f32x4 c2 = {0.f, 0.f, 0.f, 0.f};
#pragma unroll
            for (int kb = 0; kb < 16; ++kb) {
                union { unsigned long long q[2]; bf16x8 v; } a;
                const unsigned short* ap = rhg + (size_t)(b0 + l16) * HDIM + kb * 32 + kofs;
                a.q[0] = g_load64(ap);
                a.q[1] = g_load64(ap + 4);
                c2 = __builtin_amdgcn_mfma_f32_16x16x32_bf16(a.v, wp2[kb], c2, 0, 0, 0);
            }
            float hn[4];
#pragma unroll
            for (int r = 0; r < 4; ++r) {
                const float pre = c2[r] + bf2f(xh.s[r]);
                const float ht = tanhf(pre);
                hn[r] = hm[r] + zfrag[r] * (ht - hm[r]);
                hm[r] = hn[r];
                hlds[quad * 4 + r][iloc] = hn[r];          // fp32 for r-waves next step
                if (t == S_LEN - 1)
                    g_store32(hgf + (size_t)(b0 + quad * 4 + r) * HDIM + icol,
                              __float_as_uint(hn[r]));
            }
#pragma unroll
            for (int r = 0; r < 4; ++r) {
                unsigned int my = f2bf(hn[r]);
                unsigned int other = (unsigned int)__shfl_xor((int)my, 1, 64);
                if ((l16 & 1) == 0)
                    g_store32(hg + (size_t)(b0 + quad * 4 + r) * HDIM + icol, my | (other << 16));
            }
        }
        group_barrier(flags, g, j, 2u * t + 2u, tid);
    }

    // ======== final projection: out = h_T @ Wf^T + bf (fp32) ========
    if (j == 0 && tid < 16 * ODIM) {
        const int b = b0 + tid / ODIM;
        const int o = tid % ODIM;
        float acc = bfv[o];
        for (int k = 0; k < HDIM; k += 2) {
            union { unsigned long long q; float f[2]; } w;
            w.q = g_load64(hgf + (size_t)b * HDIM + k);
            acc += w.f[0] * Wf[o * HDIM + k] + w.f[1] * Wf[o * HDIM + k + 1];
        }
        out[b * ODIM + o] = acc;
    }
}

// ---------------------------------------------------------------------------
extern "C" void kernel_launch(void* const* d_in, const int* in_sizes, int n_in,
                              void* d_out, int out_size, void* d_ws, size_t ws_size,
                              hipStream_t stream)
{
    const float* x  = (const float*)d_in[0];
    const float* Wz = (const float*)d_in[1];
    const float* bz = (const float*)d_in[2];
    const float* Uz = (const float*)d_in[3];
    const float* cz = (const float*)d_in[4];
    const float* Wr = (const float*)d_in[5];
    const float* br = (const float*)d_in[6];
    const float* Ur = (const float*)d_in[7];
    const float* cr = (const float*)d_in[8];
    const float* Wh = (const float*)d_in[9];
    const float* bh = (const float*)d_in[10];
    const float* Uh = (const float*)d_in[11];
    const float* ch = (const float*)d_in[12];
    const float* Wf = (const float*)d_in[13];
    const float* bf = (const float*)d_in[14];
    float* out = (float*)d_out;

    char* ws = (char*)d_ws;
    const size_t XPB = (size_t)S_LEN * BATCH * GATES3 * sizeof(unsigned short); // 402,653,184 B
    unsigned short* xp2 = (unsigned short*)ws;
    unsigned short* hg  = (unsigned short*)(ws + XPB);                 // 65,536 B
    unsigned short* rhg = (unsigned short*)(ws + XPB + 65536);         // 65,536 B
    float*          hgf = (float*)(ws + XPB + 131072);                 // 131,072 B
    unsigned int*   flg = (unsigned int*)(ws + XPB + 262144);          // 4,096 B

    // zero h/rh state + flags (h0 = 0; epochs start at 1)
    hipMemsetAsync(ws + XPB, 0, 262144 + 4096, stream);

    proj_kernel<<<dim3((BATCH * S_LEN) / 64, GATES3 / 256), 256, 0, stream>>>(
        x, Wz, Wr, Wh, bz, cz, br, cr, bh, ch, xp2);

    gru_recur<<<dim3(64), dim3(256), 0, stream>>>(
        Uz, Ur, Uh, xp2, hg, rhg, hgf, flg, Wf, bf, out);
}

// Round 4
// 10930.050 us; speedup vs baseline: 5.8237x; 2.1951x over previous
//
#include <hip/hip_runtime.h>
#include <stdint.h>

// SimpleGRU  B=64 S=2048 I=256 H=512 O=10
//
// Phase A (proj_mfma): xp2[g][s][1536][16] (bf16) = x@[Wz|Wr|Wh]^T + (b+c), bf16 MFMA GEMM,
//   M enumerated as m = s*64+b so stores are batch-contiguous (no scatter, group-local lines).
// Phase B (gru_recur): persistent 64 blocks = 4 groups(16 batches) x 16 col-slices(32 cols).
//   U weight-stationary in VGPRs. Cross-block data via relaxed agent-scope (cache-bypassing)
//   atomics; NO fences (R2: __threadfence = L2 writeback+inv, 29 us/step).
//   R3->R4: A-fragments staged ONCE per block into LDS (was 4x/2x redundant fabric reads),
//   frag-major global layout for h / r*h (identity copy to LDS, conflict-free ds_read_b128),
//   xp prefetched one step ahead, all-waves flag polling with s_sleep.

#define S_LEN  2048
#define BATCH  64
#define IDIM   256
#define HDIM   512
#define ODIM   10
#define GATES3 1536

typedef __attribute__((ext_vector_type(8))) short bf16x8;
typedef __attribute__((ext_vector_type(4))) float f32x4;

__device__ __forceinline__ unsigned short f2bf(float x) {
    unsigned int u = __float_as_uint(x);
    u += 0x7fffu + ((u >> 16) & 1u);      // RNE
    return (unsigned short)(u >> 16);
}
__device__ __forceinline__ float bf2f(unsigned short h) {
    return __uint_as_float(((unsigned int)h) << 16);
}

// Cache-bypassing device-coherent accesses (relaxed agent atomics -> sc0 sc1 global ops).
__device__ __forceinline__ unsigned long long g_load64(const void* p) {
    return __hip_atomic_load((const unsigned long long*)p, __ATOMIC_RELAXED, __HIP_MEMORY_SCOPE_AGENT);
}
__device__ __forceinline__ void g_store32(void* p, unsigned int v) {
    __hip_atomic_store((unsigned int*)p, v, __ATOMIC_RELAXED, __HIP_MEMORY_SCOPE_AGENT);
}

// ---------------------------------------------------------------------------
// Phase A: bf16 MFMA GEMM. Tile 128(m) x 128(n), K-panels of 64, frag-major LDS.
// m = s*64 + b  (so M-tiles are 2 s-values x 64 batches; stores batch-contiguous).
// grid(12 n-tiles, 1024 m-tiles), 256 threads (4 waves, each 32 rows x 128 cols).
// ---------------------------------------------------------------------------
__global__ __launch_bounds__(256)
void proj_mfma(const float* __restrict__ x,
               const float* __restrict__ Wz, const float* __restrict__ Wr, const float* __restrict__ Wh,
               const float* __restrict__ bz, const float* __restrict__ cz,
               const float* __restrict__ br, const float* __restrict__ cr,
               const float* __restrict__ bh, const float* __restrict__ ch,
               unsigned short* __restrict__ xp2)
{
    __shared__ unsigned short As[8 * 128 * 8];   // [kcq][row][e]  16 KB
    __shared__ unsigned short Bs[8 * 128 * 8];   // 16 KB
    const int tid  = threadIdx.x;
    const int wave = tid >> 6;
    const int lane = tid & 63;
    const int quad = lane >> 4;
    const int l16  = lane & 15;
    const int nt_ = blockIdx.x;   // 0..11
    const int mt_ = blockIdx.y;   // 0..1023

    // staging: thread -> (row = tid/2, k-half = tid&1) of the 128x64 panel
    const int srow  = tid >> 1;
    const int shalf = tid & 1;
    const int mg = mt_ * 128 + srow;
    const float* axrow = x + ((size_t)(mg & 63) * S_LEN + (mg >> 6)) * IDIM + shalf * 32;
    const int ng = nt_ * 128 + srow;
    const int gt = ng >> 9, hl = ng & 511;
    const float* bxrow = (gt == 0 ? Wz : gt == 1 ? Wr : Wh) + (size_t)hl * IDIM + shalf * 32;

    f32x4 acc[2][8];
#pragma unroll
    for (int mi = 0; mi < 2; ++mi)
#pragma unroll
        for (int nj = 0; nj < 8; ++nj) {
            f32x4 z = {0.f, 0.f, 0.f, 0.f};
            acc[mi][nj] = z;
        }

    for (int kp = 0; kp < IDIM; kp += 64) {
#pragma unroll
        for (int c = 0; c < 4; ++c) {   // kcq = shalf*4 + c
            unsigned short ta[8], tb[8];
#pragma unroll
            for (int e = 0; e < 8; ++e) {
                ta[e] = f2bf(axrow[kp + c * 8 + e]);
                tb[e] = f2bf(bxrow[kp + c * 8 + e]);
            }
            const int kcq = shalf * 4 + c;
            *(bf16x8*)(As + (kcq * 128 + srow) * 8) = *(bf16x8*)ta;
            *(bf16x8*)(Bs + (kcq * 128 + srow) * 8) = *(bf16x8*)tb;
        }
        __syncthreads();
#pragma unroll
        for (int kc = 0; kc < 2; ++kc) {
            bf16x8 af[2], bfr[8];
#pragma unroll
            for (int mi = 0; mi < 2; ++mi)
                af[mi] = *(const bf16x8*)(As + ((kc * 4 + quad) * 128 + wave * 32 + mi * 16 + l16) * 8);
#pragma unroll
            for (int nj = 0; nj < 8; ++nj)
                bfr[nj] = *(const bf16x8*)(Bs + ((kc * 4 + quad) * 128 + nj * 16 + l16) * 8);
#pragma unroll
            for (int mi = 0; mi < 2; ++mi)
#pragma unroll
                for (int nj = 0; nj < 8; ++nj)
                    acc[mi][nj] = __builtin_amdgcn_mfma_f32_16x16x32_bf16(af[mi], bfr[nj], acc[mi][nj], 0, 0, 0);
        }
        __syncthreads();
    }

    // epilogue: D col=lane&15 (n), row=quad*4+r (m). rows -> b consecutive -> 8 B packed store.
    const int s_ = mt_ * 2 + (wave >> 1);
#pragma unroll
    for (int nj = 0; nj < 8; ++nj) {
        const int n  = nt_ * 128 + nj * 16 + l16;
        const int g2 = n >> 9, h2 = n & 511;
        const float bias = (g2 == 0 ? bz[h2] + cz[h2]
                          : g2 == 1 ? br[h2] + cr[h2]
                                    : bh[h2] + ch[h2]);
#pragma unroll
        for (int mi = 0; mi < 2; ++mi) {
            const int gg = (wave & 1) * 2 + mi;
            unsigned short pk[4];
#pragma unroll
            for (int r = 0; r < 4; ++r) pk[r] = f2bf(acc[mi][nj][r] + bias);
            *(unsigned long long*)(xp2 + (((size_t)gg * S_LEN + s_) * GATES3 + n) * 16 + quad * 4) =
                *(unsigned long long*)pk;
        }
    }
}

// ---------------------------------------------------------------------------
// Frag-major state layout per group (16 rows x 512 cols bf16 = 8192 elems = 16 KB):
//   idx(row, col) = (col>>5)*512 + ((col>>3)&3)*128 + row*8 + (col&7)
// Identity-copies into LDS; A-frag read = contiguous 1 KB per wave (conflict-free b128).
// ---------------------------------------------------------------------------
__device__ __forceinline__ void stage_frag(const unsigned short* __restrict__ gsrc,
                                           unsigned short* __restrict__ lds, int tid)
{
    unsigned long long v[8];
    const unsigned short* p = gsrc + tid * 32;    // 64 B per thread
#pragma unroll
    for (int i = 0; i < 8; ++i) v[i] = g_load64(p + i * 4);
    unsigned long long* q = (unsigned long long*)(lds + tid * 32);
#pragma unroll
    for (int i = 0; i < 8; ++i) q[i] = v[i];
}

// Barrier: leading __syncthreads (drains vmcnt -> bypass stores at coherence point),
// block flag store, then ALL waves poll the 16 group flags (no trailing syncthreads).
__device__ __forceinline__ void group_barrier(unsigned int* __restrict__ flags, int g, int j,
                                              unsigned int epoch, int tid, int lane)
{
    __syncthreads();
    if (tid == 0)
        __hip_atomic_store(&flags[(g * 16 + j) * 16], epoch,
                           __ATOMIC_RELAXED, __HIP_MEMORY_SCOPE_AGENT);
    if (lane < 16) {
        const unsigned int* f = &flags[(g * 16 + lane) * 16];
        while (__hip_atomic_load(f, __ATOMIC_RELAXED, __HIP_MEMORY_SCOPE_AGENT) < epoch)
            __builtin_amdgcn_s_sleep(2);
    }
}

// ---------------------------------------------------------------------------
// Phase B: 64 blocks: g = blockIdx&3 (batches 16g..), j = blockIdx>>2 (cols 32j..).
// Waves: w0,w1 = z (nt 0/1) then h~ + update; w2,w3 = r (nt 0/1).
// ---------------------------------------------------------------------------
__global__ __launch_bounds__(256)
void gru_recur(const float* __restrict__ Uz, const float* __restrict__ Ur,
               const float* __restrict__ Uh,
               const unsigned short* __restrict__ xp2,  // [g][s][1536][16] bf16
               unsigned short* __restrict__ hg,         // frag-major bf16 h    [4][8192]
               unsigned short* __restrict__ rhg,        // frag-major bf16 r*h  [4][8192]
               float* __restrict__ hgf,                 // fp32 final h [64][512]
               unsigned int* __restrict__ flags,
               const float* __restrict__ Wf, const float* __restrict__ bfv,
               float* __restrict__ out)
{
    __shared__ unsigned short ldsA[8192];   // staged h
    __shared__ unsigned short ldsB[8192];   // staged r*h
    __shared__ float hlds[16][33];          // fp32 h for r-waves
    const int tid  = threadIdx.x;
    const int wave = tid >> 6;
    const int lane = tid & 63;
    const int quad = lane >> 4;
    const int l16  = lane & 15;
    const int g  = blockIdx.x & 3;
    const int j  = blockIdx.x >> 2;
    const int b0 = g * 16;
    const int i0 = j * 32;
    const int nt = wave & 1;
    const bool isZ = (wave < 2);

    for (int i = tid; i < 16 * 33; i += 256) (&hlds[0][0])[i] = 0.f;

    // ---- weight B-fragments, stationary in VGPRs ----
    const int wrow = i0 + nt * 16 + l16;   // n = lane&15
    const int kofs = quad * 8;
    bf16x8 wp1[16], wp2[16];
    const float* U1 = isZ ? Uz : Ur;
#pragma unroll
    for (int kb = 0; kb < 16; ++kb) {
        const float* s1 = U1 + (size_t)wrow * HDIM + kb * 32 + kofs;
        const float* s2 = Uh + (size_t)wrow * HDIM + kb * 32 + kofs;
        bf16x8 w1, w2;
#pragma unroll
        for (int e = 0; e < 8; ++e) {
            w1[e] = (short)f2bf(s1[e]);
            w2[e] = (short)f2bf(s2[e]);
        }
        wp1[kb] = w1; wp2[kb] = w2;
    }

    const int iloc = nt * 16 + l16;
    const int icol = i0 + iloc;
    // producer store indices (frag-major)
    const int pidx = (icol >> 5) * 512 + ((icol >> 3) & 3) * 128 + (icol & 7);  // + row*8
    unsigned short* hgG  = hg  + g * 8192;
    unsigned short* rhgG = rhg + g * 8192;
    const unsigned short* xpg = xp2 + (size_t)g * S_LEN * GATES3 * 16;
    const int gofs1 = isZ ? 0 : HDIM;     // phase-1 gate offset (z or r)

    float zfrag[4];
    float hm[4] = {0.f, 0.f, 0.f, 0.f};   // fp32 master h (w0/w1)

    // prefetch xp for t=0
    unsigned long long xg_cur = *(const unsigned long long*)
        (xpg + ((size_t)0 * GATES3 + gofs1 + icol) * 16 + quad * 4);
    unsigned long long xh_cur = *(const unsigned long long*)
        (xpg + ((size_t)0 * GATES3 + 2 * HDIM + icol) * 16 + quad * 4);

    __syncthreads();   // hlds init visible

    for (int t = 0; t < S_LEN; ++t) {
        // ---- stage h into LDS (once per block), then phase 1 ----
        stage_frag(hgG, ldsA, tid);
        __syncthreads();

        f32x4 c1 = {0.f, 0.f, 0.f, 0.f};
#pragma unroll
        for (int kb = 0; kb < 16; ++kb) {
            const bf16x8 a = *(const bf16x8*)(ldsA + kb * 512 + quad * 128 + l16 * 8);
            c1 = __builtin_amdgcn_mfma_f32_16x16x32_bf16(a, wp1[kb], c1, 0, 0, 0);
        }
        union { unsigned long long q; unsigned short s[4]; } xq;
        xq.q = xg_cur;
        if (isZ) {
#pragma unroll
            for (int r = 0; r < 4; ++r) {
                const float pre = c1[r] + bf2f(xq.s[r]);
                zfrag[r] = 1.f / (1.f + __expf(-pre));
            }
        } else {
#pragma unroll
            for (int r = 0; r < 4; ++r) {
                const float pre = c1[r] + bf2f(xq.s[r]);
                const float v = 1.f / (1.f + __expf(-pre));
                const float rh = v * hlds[quad * 4 + r][iloc];
                unsigned int my = f2bf(rh);
                unsigned int other = (unsigned int)__shfl_xor((int)my, 1, 64);
                if ((lane & 1) == 0)
                    g_store32(rhgG + pidx + (quad * 4 + r) * 8, my | (other << 16));
            }
        }
        group_barrier(flags, g, j, 2u * (unsigned)t + 1u, tid, lane);

        // ---- stage r*h, then phase 2 (w0/w1) ----
        stage_frag(rhgG, ldsB, tid);
        __syncthreads();

        if (isZ) {
            f32x4 c2 = {0.f, 0.f, 0.f, 0.f};
#pragma unroll
            for (int kb = 0; kb < 16; ++kb) {
                const bf16x8 a = *(const bf16x8*)(ldsB + kb * 512 + quad * 128 + l16 * 8);
                c2 = __builtin_amdgcn_mfma_f32_16x16x32_bf16(a, wp2[kb], c2, 0, 0, 0);
            }
            union { unsigned long long q; unsigned short s[4]; } xh;
            xh.q = xh_cur;
            float hn[4];
#pragma unroll
            for (int r = 0; r < 4; ++r) {
                const float pre = c2[r] + bf2f(xh.s[r]);
                const float ht = tanhf(pre);
                hn[r] = hm[r] + zfrag[r] * (ht - hm[r]);
                hm[r] = hn[r];
            }
            // bypassing store of bf16 h (frag-major, packed pairs) FIRST
#pragma unroll
            for (int r = 0; r < 4; ++r) {
                unsigned int my = f2bf(hn[r]);
                unsigned int other = (unsigned int)__shfl_xor((int)my, 1, 64);
                if ((lane & 1) == 0)
                    g_store32(hgG + pidx + (quad * 4 + r) * 8, my | (other << 16));
            }
#pragma unroll
            for (int r = 0; r < 4; ++r) {
                hlds[quad * 4 + r][iloc] = hn[r];
                if (t == S_LEN - 1)
                    g_store32(hgf + (size_t)(b0 + quad * 4 + r) * HDIM + icol,
                              __float_as_uint(hn[r]));
            }
        }
        // prefetch xp for t+1 (overlaps the barrier spin)
        const int tn = (t + 1 < S_LEN) ? t + 1 : t;
        xg_cur = *(const unsigned long long*)
            (xpg + ((size_t)tn * GATES3 + gofs1 + icol) * 16 + quad * 4);
        xh_cur = *(const unsigned long long*)
            (xpg + ((size_t)tn * GATES3 + 2 * HDIM + icol) * 16 + quad * 4);

        group_barrier(flags, g, j, 2u * (unsigned)t + 2u, tid, lane);
    }

    // ---- final projection: out = h_T @ Wf^T + bf ----
    if (j == 0 && tid < 16 * ODIM) {
        const int b = b0 + tid / ODIM;
        const int o = tid % ODIM;
        float acc = bfv[o];
        for (int k = 0; k < HDIM; k += 2) {
            union { unsigned long long q; float f[2]; } w;
            w.q = g_load64(hgf + (size_t)b * HDIM + k);
            acc += w.f[0] * Wf[o * HDIM + k] + w.f[1] * Wf[o * HDIM + k + 1];
        }
        out[b * ODIM + o] = acc;
    }
}

// ---------------------------------------------------------------------------
extern "C" void kernel_launch(void* const* d_in, const int* in_sizes, int n_in,
                              void* d_out, int out_size, void* d_ws, size_t ws_size,
                              hipStream_t stream)
{
    const float* x  = (const float*)d_in[0];
    const float* Wz = (const float*)d_in[1];
    const float* bz = (const float*)d_in[2];
    const float* Uz = (const float*)d_in[3];
    const float* cz = (const float*)d_in[4];
    const float* Wr = (const float*)d_in[5];
    const float* br = (const float*)d_in[6];
    const float* Ur = (const float*)d_in[7];
    const float* cr = (const float*)d_in[8];
    const float* Wh = (const float*)d_in[9];
    const float* bh = (const float*)d_in[10];
    const float* Uh = (const float*)d_in[11];
    const float* ch = (const float*)d_in[12];
    const float* Wf = (const float*)d_in[13];
    const float* bf = (const float*)d_in[14];
    float* out = (float*)d_out;

    char* ws = (char*)d_ws;
    const size_t XPB = (size_t)S_LEN * BATCH * GATES3 * sizeof(unsigned short); // 402,653,184 B
    unsigned short* xp2 = (unsigned short*)ws;
    unsigned short* hg  = (unsigned short*)(ws + XPB);                 // 65,536 B
    unsigned short* rhg = (unsigned short*)(ws + XPB + 65536);         // 65,536 B
    float*          hgf = (float*)(ws + XPB + 131072);                 // 131,072 B
    unsigned int*   flg = (unsigned int*)(ws + XPB + 262144);          // 4,096 B

    hipMemsetAsync(ws + XPB, 0, 262144 + 4096, stream);

    proj_mfma<<<dim3(12, 1024), 256, 0, stream>>>(
        x, Wz, Wr, Wh, bz, cz, br, cr, bh, ch, xp2);

    gru_recur<<<dim3(64), dim3(256), 0, stream>>>(
        Uz, Ur, Uh, xp2, hg, rhg, hgf, flg, Wf, bf, out);
}